// Round 9
// baseline (374.861 us; speedup 1.0000x reference)
//
#include <hip/hip_runtime.h>
#include <hip/hip_bf16.h>

// GAT layer, B=2 N=4096 F_IN=256 F_OUT=64 H=4.
// pack: adj int32 -> bitmask (134MB -> 4.2MB) via __ballot, contiguous
//       256B/instr wave reads -> full HBM BW. (R7 showed direct per-lane adj
//       gather runs at 460 GB/s; this pattern is the only fast way to drink
//       the adj stream.)
// prep: x = h@W, xT bf16 [b][f][n], elT/erT f32 pre-scaled by log2e.
// main: ALL inputs cache-resident (bits 4.2MB, xT 1MB x256 reuse, erT 256KB).
//       No LDS ring, no barriers, no vmcnt in hot loop. 512-thr blocks,
//       wave = (head, j-half), 16 i-rows/block, grid 512. Scores from bit
//       tests -> P-frag; swapped PV (A=xt,B=P); denom via ones-MFMA; j-half
//       combine through LDS once at the end; direct out write (no fin).

#define NN 4096
#define NH 4
#define LOG2E 1.4426950408889634f

typedef __bf16 bf16x8 __attribute__((ext_vector_type(8)));
typedef unsigned short ushortx8 __attribute__((ext_vector_type(8)));
typedef unsigned short us4 __attribute__((ext_vector_type(4)));
typedef float f32x4 __attribute__((ext_vector_type(4)));

__device__ __forceinline__ unsigned short f2bf(float x) {
  __hip_bfloat16 hb = __float2bfloat16(x);
  return __builtin_bit_cast(unsigned short, hb);
}

#if __has_builtin(__builtin_amdgcn_exp2f)
#define EXP2F(x) __builtin_amdgcn_exp2f(x)
#else
#define EXP2F(x) exp2f(x)
#endif

// ---------------- kernel 0: pack adj to bits ----------------
// grid 2048 x 256. wave w handles row blockIdx*4+w; 64 ballot-iters of 64 j.
__global__ __launch_bounds__(256) void gat_pack(
    const int* __restrict__ adj, unsigned long long* __restrict__ adjp)
{
  const int w = threadIdx.x >> 6, l = threadIdx.x & 63;
  const int row = blockIdx.x * 4 + w;                  // b*N+i, 0..8191
  const int* src = adj + (size_t)row * NN;
  unsigned long long* dst = adjp + (size_t)row * 64;
#pragma unroll 8
  for (int it = 0; it < 64; ++it) {
    const int v = src[it * 64 + l];
    const unsigned long long m = __ballot(v != 0);
    if (l == 0) dst[it] = m;
  }
}

// ---------------- kernel 1: prep (unchanged, verified) ----------------
__global__ __launch_bounds__(256, 2) void gat_prep(
    const float* __restrict__ hmat, const float* __restrict__ W,
    const float* __restrict__ Wl, const float* __restrict__ Wr,
    unsigned short* __restrict__ xT, float* __restrict__ elT,
    float* __restrict__ erT)
{
  __shared__ __align__(16) float h_s[16][256];
  __shared__ float x_s[16][65];
  __shared__ float wlr_s[512];

  const int t  = threadIdx.x;
  const int wv = t >> 6;
  const int l  = t & 63;
  const int b  = blockIdx.x >> 8;
  const int i0 = (blockIdx.x & 255) << 4;

  {
    const float4* hsrc = (const float4*)(hmat + ((size_t)(b * NN + i0)) * 256);
    float4* hdst = (float4*)&h_s[0][0];
#pragma unroll
    for (int u = 0; u < 4; ++u) hdst[t + 256 * u] = hsrc[t + 256 * u];
    wlr_s[t]       = Wl[t];
    wlr_s[256 + t] = Wr[t];
  }
  __syncthreads();

  const int row0 = wv << 2;
  float acc[4] = {0.f, 0.f, 0.f, 0.f};
#pragma unroll 4
  for (int k4 = 0; k4 < 64; ++k4) {
    const float w0 = W[(k4 * 4 + 0) * 64 + l];
    const float w1 = W[(k4 * 4 + 1) * 64 + l];
    const float w2 = W[(k4 * 4 + 2) * 64 + l];
    const float w3 = W[(k4 * 4 + 3) * 64 + l];
#pragma unroll
    for (int rr = 0; rr < 4; ++rr) {
      const float4 hv = *(const float4*)&h_s[row0 + rr][k4 * 4];
      acc[rr] = fmaf(hv.x, w0, acc[rr]);
      acc[rr] = fmaf(hv.y, w1, acc[rr]);
      acc[rr] = fmaf(hv.z, w2, acc[rr]);
      acc[rr] = fmaf(hv.w, w3, acc[rr]);
    }
  }
#pragma unroll
  for (int rr = 0; rr < 4; ++rr) x_s[row0 + rr][l] = acc[rr];
  __syncthreads();

  if (t < 64) {
    const int row = t >> 2, hh = t & 3;
    float el = 0.f, er = 0.f;
#pragma unroll 8
    for (int f = 0; f < 64; ++f) {
      const float xv = x_s[row][f];
      el = fmaf(xv, wlr_s[hh * 64 + f], el);
      er = fmaf(xv, wlr_s[256 + hh * 64 + f], er);
    }
    elT[((size_t)b * NH + hh) * NN + i0 + row] = el * LOG2E;
    erT[((size_t)b * NH + hh) * NN + i0 + row] = er * LOG2E;
  }

  {
    const int f = t >> 2, q = t & 3;
    us4 pk;
#pragma unroll
    for (int rj = 0; rj < 4; ++rj) pk[rj] = f2bf(x_s[q * 4 + rj][f]);
    *(us4*)&xT[((size_t)(b * 64 + f)) * NN + i0 + q * 4] = pk;
  }
}

// ---------------- kernel 2: fused softmax + PV (stall-free) ----------------
// grid 512 = b(2) x itile(256); block 512 = 8 waves: wave (head h, j-half jh).
__global__ __launch_bounds__(512, 2) void gat_main(
    const unsigned long long* __restrict__ adjp,
    const unsigned short* __restrict__ xT,
    const float* __restrict__ elT, const float* __restrict__ erT,
    const float* __restrict__ bias, float* __restrict__ out)
{
  __shared__ float comb[NH][64][17];   // jh=1 partials: 16 acc + 1 denom

  const int t = threadIdx.x;
  const int w = t >> 6;
  const int l = t & 63;
  const int h  = w & 3;
  const int jh = w >> 2;
  const int b     = blockIdx.x >> 8;
  const int itile = blockIdx.x & 255;
  const int i0    = itile << 4;
  const int lrow = l & 15;
  const int lk   = l >> 4;

  const float el_reg = elT[((size_t)b * NH + h) * NN + i0 + lrow];
  // this lane's packed bit row: 32 u64 covering its 2048-j half (512B/row,
  // L1-resident after first touch; 16 lanes share each u64 -> broadcast)
  const unsigned long long* bitrow =
      adjp + ((size_t)(b * NN + i0 + lrow)) * 64 + (jh << 5);
  const float* erp =
      erT + ((size_t)b * NH + h) * NN + (jh << 11) + (lk << 3);
  const unsigned short* xtp =
      xT + (size_t)b * 64 * NN + (jh << 11) + (lk << 3);

  f32x4 acc[4] = {};
  f32x4 accd = {};
  ushortx8 ones_u;
#pragma unroll
  for (int i = 0; i < 8; ++i) ones_u[i] = 0x3F80;   // bf16 1.0
  const bf16x8 onesf = __builtin_bit_cast(bf16x8, ones_u);

#pragma unroll 2
  for (int tt = 0; tt < 32; ++tt) {
    const int jt = tt << 6;
    const unsigned long long a = bitrow[tt];
    const unsigned lo = (unsigned)a;
    const unsigned hi = (unsigned)(a >> 32);

    const float4 e0 = *(const float4*)(erp + jt);
    const float4 e1 = *(const float4*)(erp + jt + 4);
    const float4 e2 = *(const float4*)(erp + jt + 32);
    const float4 e3 = *(const float4*)(erp + jt + 36);

    bf16x8 Axt[2][4];
#pragma unroll
    for (int kc = 0; kc < 2; ++kc)
#pragma unroll
      for (int fq = 0; fq < 4; ++fq)
        Axt[kc][fq] = __builtin_bit_cast(bf16x8,
            *(const ushortx8*)(xtp + (size_t)((fq << 4) + lrow) * NN + jt + (kc << 5)));

#pragma unroll
    for (int kc = 0; kc < 2; ++kc) {
      const unsigned by = ((kc ? hi : lo) >> (lk << 3)) & 0xffu;
      const float4 ea = kc ? e2 : e0;
      const float4 eb = kc ? e3 : e1;

      ushortx8 pa;
#define SCORE(BIT_, E_, IDX) { \
      float s_  = el_reg + (E_); \
      float lr_ = fmaxf(s_, 0.2f * s_); \
      float w_  = (by & (BIT_)) ? EXP2F(lr_) : 0.0f; \
      pa[IDX] = f2bf(w_); }
      SCORE(1u,   ea.x, 0) SCORE(2u,   ea.y, 1)
      SCORE(4u,   ea.z, 2) SCORE(8u,   ea.w, 3)
      SCORE(16u,  eb.x, 4) SCORE(32u,  eb.y, 5)
      SCORE(64u,  eb.z, 6) SCORE(128u, eb.w, 7)
#undef SCORE

      const bf16x8 P = __builtin_bit_cast(bf16x8, pa);
      // swapped PV: D[f][i] = sum_j xt[f][j] * P[j][i]
      accd = __builtin_amdgcn_mfma_f32_16x16x32_bf16(onesf, P, accd, 0, 0, 0);
#pragma unroll
      for (int fq = 0; fq < 4; ++fq)
        acc[fq] = __builtin_amdgcn_mfma_f32_16x16x32_bf16(
            Axt[kc][fq], P, acc[fq], 0, 0, 0);
    }
  }

  // ---- combine j-halves through LDS (stride 17 -> conflict-free) ----
  if (jh == 1) {
#pragma unroll
    for (int fq = 0; fq < 4; ++fq)
#pragma unroll
      for (int rr = 0; rr < 4; ++rr)
        comb[h][l][(fq << 2) + rr] = acc[fq][rr];
    comb[h][l][16] = accd[0];
  }
  __syncthreads();
  if (jh == 0) {
#pragma unroll
    for (int fq = 0; fq < 4; ++fq)
#pragma unroll
      for (int rr = 0; rr < 4; ++rr)
        acc[fq][rr] += comb[h][l][(fq << 2) + rr];
    const float d = accd[0] + comb[h][l][16];
    const float inv = 1.0f / d;

    // C row = f = fq*16 + lk*4 + rr, col = i = lrow
    const size_t obase = ((size_t)(b * NN + i0 + lrow) * NH + h) << 6;
#pragma unroll
    for (int fq = 0; fq < 4; ++fq) {
      const int f0 = (fq << 4) + (lk << 2);
      const float4 bv = *(const float4*)&bias[f0];
      float4 v = {acc[fq][0] * inv + bv.x, acc[fq][1] * inv + bv.y,
                  acc[fq][2] * inv + bv.z, acc[fq][3] * inv + bv.w};
      v.x = v.x > 0.f ? v.x : (__expf(v.x) - 1.f);
      v.y = v.y > 0.f ? v.y : (__expf(v.y) - 1.f);
      v.z = v.z > 0.f ? v.z : (__expf(v.z) - 1.f);
      v.w = v.w > 0.f ? v.w : (__expf(v.w) - 1.f);
      *(float4*)&out[obase + f0] = v;
    }
  }
}

extern "C" void kernel_launch(void* const* d_in, const int* in_sizes, int n_in,
                              void* d_out, int out_size, void* d_ws, size_t ws_size,
                              hipStream_t stream) {
  const int*   adj  = (const int*)d_in[0];
  const float* hmat = (const float*)d_in[1];
  const float* W    = (const float*)d_in[2];
  const float* Wl   = (const float*)d_in[3];
  const float* Wr   = (const float*)d_in[4];
  const float* bias = (const float*)d_in[5];
  float* out = (float*)d_out;

  char* wsb = (char*)d_ws;
  unsigned short*     xT   = (unsigned short*)wsb;                 // 1 MB
  float*              elT  = (float*)(wsb + 1048576);              // 128 KB
  float*              erT  = (float*)(wsb + 1179648);              // 128 KB
  unsigned long long* adjp = (unsigned long long*)(wsb + 1310720); // 4 MB

  gat_pack<<<2048, 256, 0, stream>>>(adj, adjp);
  gat_prep<<<512, 256, 0, stream>>>(hmat, W, Wl, Wr, xT, elT, erT);
  gat_main<<<512, 512, 0, stream>>>(adjp, xT, elT, erT, bias, out);
}

// Round 10
// 280.774 us; speedup vs baseline: 1.3351x; 1.3351x over previous
//
#include <hip/hip_runtime.h>
#include <hip/hip_bf16.h>

// GAT layer, B=2 N=4096 F_IN=256 F_OUT=64 H=4.
// R10: every hot-loop load is wave-contiguous (R9 died of per-instr segment
// divergence: 16 cache lines per xt/bit load -> TA serialization).
// pack: adj int32 -> bitmask (134MB -> 4.2MB) via __ballot (full-BW stream).
// prep: x = h@W; writes xtF in PRE-SWIZZLED MFMA fragment order
//       [b][tile64][kc][fq][lane][8] -> main's xt loads = 1KB contiguous.
//       elT/erT f32, pre-scaled by log2e.
// main: block 512 = 8 waves = (head-pair hp x j-slice js); 16 i-rows.
//       Bit tile (8KB) staged to LDS once (1 barrier); per tile: 1 ds_read_b64
//       broadcast + 8 contiguous xt loads + 8 er loads. Scores -> cvt_pk bf16
//       pairs -> swapped PV MFMA; denom via ones-MFMA; LDS tree-combine of 4
//       j-slices; direct out write.

#define NN 4096
#define NH 4
#define LOG2E 1.4426950408889634f

typedef __bf16 bf16x8 __attribute__((ext_vector_type(8)));
typedef unsigned short ushortx8 __attribute__((ext_vector_type(8)));
typedef unsigned short us4 __attribute__((ext_vector_type(4)));
typedef float f32x4 __attribute__((ext_vector_type(4)));
typedef unsigned long long u64;
typedef unsigned int u32;

__device__ __forceinline__ unsigned short f2bf(float x) {
  __hip_bfloat16 hb = __float2bfloat16(x);
  return __builtin_bit_cast(unsigned short, hb);
}

#if __has_builtin(__builtin_amdgcn_exp2f)
#define EXP2F(x) __builtin_amdgcn_exp2f(x)
#else
#define EXP2F(x) exp2f(x)
#endif

// one packed pair of masked-softmax weights (RNE via v_cvt_pk_bf16_f32)
#define SCPAIR(DST, BY, BIT, EL, E0, E1) { \
  float s0_ = (EL) + (E0); \
  float w0_ = (((BY) >> (BIT)) & 1u) ? EXP2F(fmaxf(s0_, 0.2f * s0_)) : 0.0f; \
  float s1_ = (EL) + (E1); \
  float w1_ = (((BY) >> ((BIT) + 1)) & 1u) ? EXP2F(fmaxf(s1_, 0.2f * s1_)) : 0.0f; \
  asm("v_cvt_pk_bf16_f32 %0, %1, %2" : "=v"(DST) : "v"(w0_), "v"(w1_)); }

#define SCORE8(PA, BY, EL, EA, EB) { \
  uint4 pk_; \
  SCPAIR(pk_.x, BY, 0, EL, (EA).x, (EA).y) \
  SCPAIR(pk_.y, BY, 2, EL, (EA).z, (EA).w) \
  SCPAIR(pk_.z, BY, 4, EL, (EB).x, (EB).y) \
  SCPAIR(pk_.w, BY, 6, EL, (EB).z, (EB).w) \
  PA = __builtin_bit_cast(bf16x8, pk_); }

// ---------------- kernel 0: pack adj to bits ----------------
__global__ __launch_bounds__(256) void gat_pack(
    const int* __restrict__ adj, u64* __restrict__ adjp)
{
  const int w = threadIdx.x >> 6, l = threadIdx.x & 63;
  const int row = blockIdx.x * 4 + w;                  // b*N+i
  const int* src = adj + (size_t)row * NN;
  u64* dst = adjp + (size_t)row * 64;
#pragma unroll 8
  for (int it = 0; it < 64; ++it) {
    const int v = src[it * 64 + l];
    const u64 m = __ballot(v != 0);
    if (l == 0) dst[it] = m;
  }
}

// ---------------- kernel 1: prep ----------------
__global__ __launch_bounds__(256, 2) void gat_prep(
    const float* __restrict__ hmat, const float* __restrict__ W,
    const float* __restrict__ Wl, const float* __restrict__ Wr,
    unsigned short* __restrict__ xtF, float* __restrict__ elT,
    float* __restrict__ erT)
{
  __shared__ __align__(16) float h_s[16][256];
  __shared__ float x_s[16][65];
  __shared__ float wlr_s[512];

  const int t  = threadIdx.x;
  const int wv = t >> 6;
  const int l  = t & 63;
  const int b  = blockIdx.x >> 8;
  const int i0 = (blockIdx.x & 255) << 4;   // this block's 16 source rows (j)

  {
    const float4* hsrc = (const float4*)(hmat + ((size_t)(b * NN + i0)) * 256);
    float4* hdst = (float4*)&h_s[0][0];
#pragma unroll
    for (int u = 0; u < 4; ++u) hdst[t + 256 * u] = hsrc[t + 256 * u];
    wlr_s[t]       = Wl[t];
    wlr_s[256 + t] = Wr[t];
  }
  __syncthreads();

  const int row0 = wv << 2;
  float acc[4] = {0.f, 0.f, 0.f, 0.f};
#pragma unroll 4
  for (int k4 = 0; k4 < 64; ++k4) {
    const float w0 = W[(k4 * 4 + 0) * 64 + l];
    const float w1 = W[(k4 * 4 + 1) * 64 + l];
    const float w2 = W[(k4 * 4 + 2) * 64 + l];
    const float w3 = W[(k4 * 4 + 3) * 64 + l];
#pragma unroll
    for (int rr = 0; rr < 4; ++rr) {
      const float4 hv = *(const float4*)&h_s[row0 + rr][k4 * 4];
      acc[rr] = fmaf(hv.x, w0, acc[rr]);
      acc[rr] = fmaf(hv.y, w1, acc[rr]);
      acc[rr] = fmaf(hv.z, w2, acc[rr]);
      acc[rr] = fmaf(hv.w, w3, acc[rr]);
    }
  }
#pragma unroll
  for (int rr = 0; rr < 4; ++rr) x_s[row0 + rr][l] = acc[rr];
  __syncthreads();

  if (t < 64) {
    const int row = t >> 2, hh = t & 3;
    float el = 0.f, er = 0.f;
#pragma unroll 8
    for (int f = 0; f < 64; ++f) {
      const float xv = x_s[row][f];
      el = fmaf(xv, wlr_s[hh * 64 + f], el);
      er = fmaf(xv, wlr_s[256 + hh * 64 + f], er);
    }
    elT[((size_t)b * NH + hh) * NN + i0 + row] = el * LOG2E;
    erT[((size_t)b * NH + hh) * NN + i0 + row] = er * LOG2E;
  }

  // xtF write: fragment order [b][tile][kc][fq][lane=lk*16+lrow][e]
  {
    const int f = t >> 2, q = t & 3;
    const int jo = (i0 & 63) + q * 4;        // within-64-tile j offset
    const size_t off = ((size_t)(b * 64 + (i0 >> 6)) << 12)
                     + ((size_t)(((jo >> 5) & 1) * 4 + (f >> 4)) << 9)
                     + ((size_t)(((jo >> 3) & 3) * 16 + (f & 15)) << 3)
                     + (jo & 7);
    us4 pk;
#pragma unroll
    for (int rj = 0; rj < 4; ++rj) pk[rj] = f2bf(x_s[q * 4 + rj][f]);
    *(us4*)&xtF[off] = pk;
  }
}

// ---------------- kernel 2: fused softmax + PV ----------------
// grid 512 = b(2) x itile(256); block 512 = 8 waves = (hp 0/1, js 0..3).
__global__ __launch_bounds__(512, 2) void gat_main(
    const u64* __restrict__ adjp, const unsigned short* __restrict__ xtF,
    const float* __restrict__ elT, const float* __restrict__ erT,
    const float* __restrict__ bias, float* __restrict__ out)
{
  __shared__ __align__(16) u64 bits_lds[16][66];      // 8.25 KB, padded
  __shared__ __align__(16) float comb[4][2][64][20];  // 40 KB tree buffer

  const int t = threadIdx.x;
  const int w = t >> 6, l = t & 63;
  const int hp = w >> 2, js = w & 3;
  const int b = blockIdx.x >> 8;
  const int i0 = (blockIdx.x & 255) << 4;
  const int lrow = l & 15, lk = l >> 4;

  {  // stage the block's 8KB bit tile, fully coalesced (16 rows x 64 u64)
    const u64* bsrc = adjp + ((size_t)(b * NN + i0)) * 64;
    bits_lds[t >> 6][t & 63]       = bsrc[t];
    bits_lds[8 + (t >> 6)][t & 63] = bsrc[512 + t];
  }
  __syncthreads();

  const float el0 = elT[((size_t)(b * NH) + hp * 2 + 0) * NN + i0 + lrow];
  const float el1 = elT[((size_t)(b * NH) + hp * 2 + 1) * NN + i0 + lrow];

  const float* e0base = erT + ((size_t)(b * NH) + hp * 2) * NN + (js << 10) + (lk << 3);
  const unsigned short* xbase = xtF + ((size_t)(b * 64 + (js << 4)) << 12) + (l << 3);

  f32x4 acc[2][4] = {};
  f32x4 accd[2] = {};
  ushortx8 ones_u;
#pragma unroll
  for (int i = 0; i < 8; ++i) ones_u[i] = 0x3F80;
  const bf16x8 onesf = __builtin_bit_cast(bf16x8, ones_u);

#pragma unroll 2
  for (int tt = 0; tt < 16; ++tt) {
    // bits: ds_read_b64, 16-lane broadcast, padded stride -> ~conflict-free
    const u64 a = bits_lds[lrow][(js << 4) + tt];
    const u32 by0 = ((u32)a >> (lk << 3)) & 0xffu;
    const u32 by1 = ((u32)(a >> 32) >> (lk << 3)) & 0xffu;

    // xt fragments: 8 x contiguous-1KB loads
    const unsigned short* xb = xbase + ((size_t)tt << 12);
    bf16x8 X[2][4];
#pragma unroll
    for (int kc = 0; kc < 2; ++kc)
#pragma unroll
      for (int fq = 0; fq < 4; ++fq)
        X[kc][fq] = __builtin_bit_cast(bf16x8,
            *(const ushortx8*)(xb + ((kc * 4 + fq) << 9)));

    // er windows for both heads (16-lane broadcast, 1-2 lines per instr)
    const float* ep0 = e0base + (tt << 6);
    const float* ep1 = ep0 + NN;
    const float4 ea0 = *(const float4*)(ep0);
    const float4 eb0 = *(const float4*)(ep0 + 4);
    const float4 ec0 = *(const float4*)(ep0 + 32);
    const float4 ed0 = *(const float4*)(ep0 + 36);
    const float4 ea1 = *(const float4*)(ep1);
    const float4 eb1 = *(const float4*)(ep1 + 4);
    const float4 ec1 = *(const float4*)(ep1 + 32);
    const float4 ed1 = *(const float4*)(ep1 + 36);

    bf16x8 P00, P01, P10, P11;
    SCORE8(P00, by0, el0, ea0, eb0);
    SCORE8(P01, by1, el0, ec0, ed0);
    SCORE8(P10, by0, el1, ea1, eb1);
    SCORE8(P11, by1, el1, ec1, ed1);

    accd[0] = __builtin_amdgcn_mfma_f32_16x16x32_bf16(onesf, P00, accd[0], 0, 0, 0);
    accd[1] = __builtin_amdgcn_mfma_f32_16x16x32_bf16(onesf, P10, accd[1], 0, 0, 0);
#pragma unroll
    for (int fq = 0; fq < 4; ++fq)
      acc[0][fq] = __builtin_amdgcn_mfma_f32_16x16x32_bf16(X[0][fq], P00, acc[0][fq], 0, 0, 0);
#pragma unroll
    for (int fq = 0; fq < 4; ++fq)
      acc[1][fq] = __builtin_amdgcn_mfma_f32_16x16x32_bf16(X[0][fq], P10, acc[1][fq], 0, 0, 0);
    accd[0] = __builtin_amdgcn_mfma_f32_16x16x32_bf16(onesf, P01, accd[0], 0, 0, 0);
    accd[1] = __builtin_amdgcn_mfma_f32_16x16x32_bf16(onesf, P11, accd[1], 0, 0, 0);
#pragma unroll
    for (int fq = 0; fq < 4; ++fq)
      acc[0][fq] = __builtin_amdgcn_mfma_f32_16x16x32_bf16(X[1][fq], P01, acc[0][fq], 0, 0, 0);
#pragma unroll
    for (int fq = 0; fq < 4; ++fq)
      acc[1][fq] = __builtin_amdgcn_mfma_f32_16x16x32_bf16(X[1][fq], P11, acc[1][fq], 0, 0, 0);
  }

  // ---- tree-combine the 4 j-slices (per head-pair) ----
  auto cwrite = [&](int slot) {
#pragma unroll
    for (int hh = 0; hh < 2; ++hh) {
#pragma unroll
      for (int fq = 0; fq < 4; ++fq)
        *(f32x4*)&comb[slot][hh][l][fq << 2] = acc[hh][fq];
      comb[slot][hh][l][16] = accd[hh][0];
    }
  };
  auto cadd = [&](int slot) {
#pragma unroll
    for (int hh = 0; hh < 2; ++hh) {
#pragma unroll
      for (int fq = 0; fq < 4; ++fq) {
        const f32x4 v = *(const f32x4*)&comb[slot][hh][l][fq << 2];
#pragma unroll
        for (int rr = 0; rr < 4; ++rr) acc[hh][fq][rr] += v[rr];
      }
      accd[hh][0] += comb[slot][hh][l][16];
    }
  };

  if (js >= 2) cwrite(hp * 2 + js - 2);
  __syncthreads();
  if (js < 2) cadd(hp * 2 + js);
  __syncthreads();
  if (js == 1) cwrite(hp * 2);
  __syncthreads();
  if (js == 0) {
    cadd(hp * 2);
#pragma unroll
    for (int hh = 0; hh < 2; ++hh) {
      const float inv = 1.0f / accd[hh][0];
      const size_t obase =
          ((size_t)(b * NN + i0 + lrow) * NH + hp * 2 + hh) << 6;
#pragma unroll
      for (int fq = 0; fq < 4; ++fq) {
        const int f0 = (fq << 4) + (lk << 2);
        const float4 bv = *(const float4*)&bias[f0];
        float4 v = {acc[hh][fq][0] * inv + bv.x, acc[hh][fq][1] * inv + bv.y,
                    acc[hh][fq][2] * inv + bv.z, acc[hh][fq][3] * inv + bv.w};
        v.x = v.x > 0.f ? v.x : (__expf(v.x) - 1.f);
        v.y = v.y > 0.f ? v.y : (__expf(v.y) - 1.f);
        v.z = v.z > 0.f ? v.z : (__expf(v.z) - 1.f);
        v.w = v.w > 0.f ? v.w : (__expf(v.w) - 1.f);
        *(float4*)&out[obase + f0] = v;
      }
    }
  }
}

extern "C" void kernel_launch(void* const* d_in, const int* in_sizes, int n_in,
                              void* d_out, int out_size, void* d_ws, size_t ws_size,
                              hipStream_t stream) {
  const int*   adj  = (const int*)d_in[0];
  const float* hmat = (const float*)d_in[1];
  const float* W    = (const float*)d_in[2];
  const float* Wl   = (const float*)d_in[3];
  const float* Wr   = (const float*)d_in[4];
  const float* bias = (const float*)d_in[5];
  float* out = (float*)d_out;

  char* wsb = (char*)d_ws;
  unsigned short* xtF  = (unsigned short*)wsb;            // 1 MB
  float*          elT  = (float*)(wsb + 1048576);         // 128 KB
  float*          erT  = (float*)(wsb + 1179648);         // 128 KB
  u64*            adjp = (u64*)(wsb + 1310720);           // 4 MB

  gat_pack<<<2048, 256, 0, stream>>>(adj, adjp);
  gat_prep<<<512, 256, 0, stream>>>(hmat, W, Wl, Wr, xtF, elT, erT);
  gat_main<<<512, 512, 0, stream>>>(adjp, xtF, elT, erT, bias, out);
}